// Round 1
// baseline (1147.206 us; speedup 1.0000x reference)
//
#include <hip/hip_runtime.h>

// LossClassInOut: pred, pseudo are [N=2e6, C=32] fp32. Output: scalar fp32.
//
// ws float layout (2176 floats = 8704 B):
//   [0,32)      counts_a   (pred stats, segmented by pseudo labels)
//   [32,64)     counts_b   (pseudo stats, segmented by pred labels)
//   [64,1088)   sums_a [32][32]
//   [1088,2112) sums_b [32][32]
//   [2112,2144) intra_a
//   [2144,2176) intra_b

constexpr int CDIM = 32;
constexpr int SPAD = 33;   // LDS pad: bank = (c*33+d)%32 = (c+d)%32 spreads classes

// argmax over one row (32 floats) held as float4 across 8 consecutive lanes.
// Lexicographic max on (value, -index) => first-index tie-break, associative.
__device__ __forceinline__ int argmax8(float4 v, int j) {
    float best = v.x; int bi = j * 4;
    if (v.y > best) { best = v.y; bi = j * 4 + 1; }
    if (v.z > best) { best = v.z; bi = j * 4 + 2; }
    if (v.w > best) { best = v.w; bi = j * 4 + 3; }
#pragma unroll
    for (int m = 1; m < 8; m <<= 1) {
        float ob = __shfl_xor(best, m, 64);
        int   oi = __shfl_xor(bi,   m, 64);
        if (ob > best || (ob == best && oi < bi)) { best = ob; bi = oi; }
    }
    return bi;
}

__global__ __launch_bounds__(256) void pass1_kernel(
    const float* __restrict__ pred, const float* __restrict__ pseudo,
    float* __restrict__ ws, int nrows)
{
    __shared__ float sa[CDIM * SPAD];
    __shared__ float sb[CDIM * SPAD];
    __shared__ float ca[CDIM];
    __shared__ float cb[CDIM];
    int t = threadIdx.x;
    for (int i = t; i < CDIM * SPAD; i += 256) { sa[i] = 0.f; sb[i] = 0.f; }
    if (t < CDIM) { ca[t] = 0.f; cb[t] = 0.f; }
    __syncthreads();

    const int j  = t & 7;        // float4 quad within row
    const int rw = t >> 3;       // row slot within block (0..31)
    long long row    = (long long)blockIdx.x * 32 + rw;
    long long stride = (long long)gridDim.x * 32;
    const float4* p4p = (const float4*)pred;
    const float4* q4p = (const float4*)pseudo;

    for (; row < nrows; row += stride) {
        float4 p = p4p[row * 8 + j];
        float4 q = q4p[row * 8 + j];
        int la = argmax8(q, j);   // pseudo label -> segments pred
        int lb = argmax8(p, j);   // pred label   -> segments pseudo
        int ba = la * SPAD + j * 4;
        atomicAdd(&sa[ba + 0], p.x); atomicAdd(&sa[ba + 1], p.y);
        atomicAdd(&sa[ba + 2], p.z); atomicAdd(&sa[ba + 3], p.w);
        int bb = lb * SPAD + j * 4;
        atomicAdd(&sb[bb + 0], q.x); atomicAdd(&sb[bb + 1], q.y);
        atomicAdd(&sb[bb + 2], q.z); atomicAdd(&sb[bb + 3], q.w);
        if (j == 0) { atomicAdd(&ca[la], 1.0f); atomicAdd(&cb[lb], 1.0f); }
    }
    __syncthreads();

    for (int i = t; i < CDIM * CDIM; i += 256) {
        int c = i >> 5, d = i & 31;
        atomicAdd(&ws[64 + i],        sa[c * SPAD + d]);
        atomicAdd(&ws[64 + 1024 + i], sb[c * SPAD + d]);
    }
    if (t < CDIM) { atomicAdd(&ws[t], ca[t]); atomicAdd(&ws[32 + t], cb[t]); }
}

__global__ __launch_bounds__(256) void pass2_kernel(
    const float* __restrict__ pred, const float* __restrict__ pseudo,
    float* __restrict__ ws, int nrows)
{
    __shared__ float ma[CDIM * SPAD];
    __shared__ float mb[CDIM * SPAD];
    __shared__ float ia[CDIM];
    __shared__ float ib[CDIM];
    int t = threadIdx.x;
    for (int i = t; i < CDIM * CDIM; i += 256) {
        int c = i >> 5, d = i & 31;
        ma[c * SPAD + d] = ws[64 + i]        / fmaxf(ws[c],      1.0f);
        mb[c * SPAD + d] = ws[64 + 1024 + i] / fmaxf(ws[32 + c], 1.0f);
    }
    if (t < CDIM) { ia[t] = 0.f; ib[t] = 0.f; }
    __syncthreads();

    const int j  = t & 7;
    const int rw = t >> 3;
    long long row    = (long long)blockIdx.x * 32 + rw;
    long long stride = (long long)gridDim.x * 32;
    const float4* p4p = (const float4*)pred;
    const float4* q4p = (const float4*)pseudo;

    for (; row < nrows; row += stride) {
        float4 p = p4p[row * 8 + j];
        float4 q = q4p[row * 8 + j];
        int la = argmax8(q, j);
        int lb = argmax8(p, j);
        const float* mra = ma + la * SPAD + j * 4;
        float pa_ = fabsf(p.x - mra[0]) + fabsf(p.y - mra[1]) +
                    fabsf(p.z - mra[2]) + fabsf(p.w - mra[3]);
        const float* mrb = mb + lb * SPAD + j * 4;
        float pb_ = fabsf(q.x - mrb[0]) + fabsf(q.y - mrb[1]) +
                    fabsf(q.z - mrb[2]) + fabsf(q.w - mrb[3]);
#pragma unroll
        for (int m = 1; m < 8; m <<= 1) {
            pa_ += __shfl_xor(pa_, m, 64);
            pb_ += __shfl_xor(pb_, m, 64);
        }
        if (j == 0) { atomicAdd(&ia[la], pa_); atomicAdd(&ib[lb], pb_); }
    }
    __syncthreads();
    if (t < CDIM) {
        atomicAdd(&ws[2112 + t], ia[t]);
        atomicAdd(&ws[2144 + t], ib[t]);
    }
}

__global__ __launch_bounds__(64) void finalize_kernel(
    const float* __restrict__ ws, float* __restrict__ out, int nrows)
{
    __shared__ float tota[CDIM];
    __shared__ float totb[CDIM];
    int t = threadIdx.x;   // one wave: lanes 0..31 = tensor a, 32..63 = tensor b
    if (t < CDIM) {
        float sa_ = 0.f, sb_ = 0.f;
        for (int c = 0; c < CDIM; c++) {
            sa_ += ws[64 + c * 32 + t];
            sb_ += ws[64 + 1024 + c * 32 + t];
        }
        tota[t] = sa_; totb[t] = sb_;
    }
    __syncthreads();

    const int  c   = t & 31;
    const bool isA = (t < 32);
    const float* sums = isA ? (ws + 64) : (ws + 64 + 1024);
    const float* tot  = isA ? tota : totb;
    float cnt  = isA ? ws[c]        : ws[32 + c];
    float isum = isA ? ws[2112 + c] : ws[2144 + c];

    float safe = fmaxf(cnt, 1.0f);
    float invs = 1.0f / safe;
    float invo = 1.0f / fmaxf((float)nrows - cnt, 1.0f);
    float mad = 0.f;
    for (int d = 0; d < CDIM; d++) {
        float s = sums[c * 32 + d];
        float m = s * invs;                  // class mean
        float o = (tot[d] - s) * invo;       // complement mean
        mad += fabsf(m - o);
    }
    mad *= (1.0f / CDIM);
    float diff = expf(-5.0f * mad);
    float present = (cnt > 0.f) ? 1.f : 0.f;

    unsigned long long pm = __ballot(cnt > 0.f);
    int np = isA ? __popcll(pm & 0xFFFFFFFFull) : __popcll(pm >> 32);
    if (np <= 1) diff = 1.0f;                // only-one-class branch

    float intra   = isum * invs * (1.0f / CDIM);
    float contrib = present * (intra + diff);
    float pres    = present;
#pragma unroll
    for (int m = 1; m < 64; m <<= 1) {
        contrib += __shfl_xor(contrib, m, 64);
        pres    += __shfl_xor(pres,    m, 64);
    }
    if (t == 0) out[0] = contrib / (2.0f * pres);
}

extern "C" void kernel_launch(void* const* d_in, const int* in_sizes, int n_in,
                              void* d_out, int out_size, void* d_ws, size_t ws_size,
                              hipStream_t stream) {
    const float* pred   = (const float*)d_in[0];
    const float* pseudo = (const float*)d_in[1];
    float* ws  = (float*)d_ws;
    float* out = (float*)d_out;
    const int nrows = in_sizes[0] / CDIM;   // 2,000,000

    // ws is poisoned 0xAA before every timed launch — zero the accumulators.
    hipMemsetAsync(d_ws, 0, 2176 * sizeof(float), stream);

    dim3 grid(2048), block(256);  // 8 blocks/CU * 256 CUs; LDS ~8.7KB => wave-limited
    pass1_kernel<<<grid, block, 0, stream>>>(pred, pseudo, ws, nrows);
    pass2_kernel<<<grid, block, 0, stream>>>(pred, pseudo, ws, nrows);
    finalize_kernel<<<1, 64, 0, stream>>>(ws, out, nrows);
}

// Round 2
// 1143.872 us; speedup vs baseline: 1.0029x; 1.0029x over previous
//
#include <hip/hip_runtime.h>

// LossClassInOut: pred, pseudo are [N=2e6, C=32] fp32. Output: scalar fp32.
//
// ws float layout (2176 floats = 8704 B):
//   [0,32)      counts_a   (pred stats, segmented by pseudo labels)
//   [32,64)     counts_b   (pseudo stats, segmented by pred labels)
//   [64,1088)   sums_a [32][32]
//   [1088,2112) sums_b [32][32]
//   [2112,2144) intra_a
//   [2144,2176) intra_b
//
// R1 lesson: fp32 atomicAdd w/o -munsafe-fp-atomics compiles to a CAS retry
// loop; 2048-way same-address contention on ws made each pass ~500-700 us of
// pure serialization. unsafeAtomicAdd emits hw ds_add_f32 / global_atomic_add_f32.

constexpr int CDIM = 32;
constexpr int SPAD = 33;   // LDS pad: bank = (c*33+d)%32 = (c+d)%32 spreads classes

__device__ __forceinline__ void lds_fadd(float* p, float v)    { unsafeAtomicAdd(p, v); }
__device__ __forceinline__ void glob_fadd(float* p, float v)   { unsafeAtomicAdd(p, v); }

// argmax over one row (32 floats) held as float4 across 8 consecutive lanes.
// Lexicographic max on (value, -index) => first-index tie-break, associative.
__device__ __forceinline__ int argmax8(float4 v, int j) {
    float best = v.x; int bi = j * 4;
    if (v.y > best) { best = v.y; bi = j * 4 + 1; }
    if (v.z > best) { best = v.z; bi = j * 4 + 2; }
    if (v.w > best) { best = v.w; bi = j * 4 + 3; }
#pragma unroll
    for (int m = 1; m < 8; m <<= 1) {
        float ob = __shfl_xor(best, m, 64);
        int   oi = __shfl_xor(bi,   m, 64);
        if (ob > best || (ob == best && oi < bi)) { best = ob; bi = oi; }
    }
    return bi;
}

__global__ __launch_bounds__(256) void pass1_kernel(
    const float* __restrict__ pred, const float* __restrict__ pseudo,
    float* __restrict__ ws, int nrows)
{
    __shared__ float sa[CDIM * SPAD];
    __shared__ float sb[CDIM * SPAD];
    __shared__ float ca[CDIM];
    __shared__ float cb[CDIM];
    int t = threadIdx.x;
    for (int i = t; i < CDIM * SPAD; i += 256) { sa[i] = 0.f; sb[i] = 0.f; }
    if (t < CDIM) { ca[t] = 0.f; cb[t] = 0.f; }
    __syncthreads();

    const int j  = t & 7;        // float4 quad within row
    const int rw = t >> 3;       // row slot within block (0..31)
    long long row    = (long long)blockIdx.x * 32 + rw;
    long long stride = (long long)gridDim.x * 32;
    const float4* p4p = (const float4*)pred;
    const float4* q4p = (const float4*)pseudo;

    for (; row < nrows; row += stride) {
        float4 p = p4p[row * 8 + j];
        float4 q = q4p[row * 8 + j];
        int la = argmax8(q, j);   // pseudo label -> segments pred
        int lb = argmax8(p, j);   // pred label   -> segments pseudo
        int ba = la * SPAD + j * 4;
        lds_fadd(&sa[ba + 0], p.x); lds_fadd(&sa[ba + 1], p.y);
        lds_fadd(&sa[ba + 2], p.z); lds_fadd(&sa[ba + 3], p.w);
        int bb = lb * SPAD + j * 4;
        lds_fadd(&sb[bb + 0], q.x); lds_fadd(&sb[bb + 1], q.y);
        lds_fadd(&sb[bb + 2], q.z); lds_fadd(&sb[bb + 3], q.w);
        if (j == 0) { lds_fadd(&ca[la], 1.0f); lds_fadd(&cb[lb], 1.0f); }
    }
    __syncthreads();

    for (int i = t; i < CDIM * CDIM; i += 256) {
        int c = i >> 5, d = i & 31;
        glob_fadd(&ws[64 + i],        sa[c * SPAD + d]);
        glob_fadd(&ws[64 + 1024 + i], sb[c * SPAD + d]);
    }
    if (t < CDIM) { glob_fadd(&ws[t], ca[t]); glob_fadd(&ws[32 + t], cb[t]); }
}

__global__ __launch_bounds__(256) void pass2_kernel(
    const float* __restrict__ pred, const float* __restrict__ pseudo,
    float* __restrict__ ws, int nrows)
{
    __shared__ float ma[CDIM * SPAD];
    __shared__ float mb[CDIM * SPAD];
    __shared__ float ia[CDIM];
    __shared__ float ib[CDIM];
    int t = threadIdx.x;
    for (int i = t; i < CDIM * CDIM; i += 256) {
        int c = i >> 5, d = i & 31;
        ma[c * SPAD + d] = ws[64 + i]        / fmaxf(ws[c],      1.0f);
        mb[c * SPAD + d] = ws[64 + 1024 + i] / fmaxf(ws[32 + c], 1.0f);
    }
    if (t < CDIM) { ia[t] = 0.f; ib[t] = 0.f; }
    __syncthreads();

    const int j  = t & 7;
    const int rw = t >> 3;
    long long row    = (long long)blockIdx.x * 32 + rw;
    long long stride = (long long)gridDim.x * 32;
    const float4* p4p = (const float4*)pred;
    const float4* q4p = (const float4*)pseudo;

    for (; row < nrows; row += stride) {
        float4 p = p4p[row * 8 + j];
        float4 q = q4p[row * 8 + j];
        int la = argmax8(q, j);
        int lb = argmax8(p, j);
        const float* mra = ma + la * SPAD + j * 4;
        float pa_ = fabsf(p.x - mra[0]) + fabsf(p.y - mra[1]) +
                    fabsf(p.z - mra[2]) + fabsf(p.w - mra[3]);
        const float* mrb = mb + lb * SPAD + j * 4;
        float pb_ = fabsf(q.x - mrb[0]) + fabsf(q.y - mrb[1]) +
                    fabsf(q.z - mrb[2]) + fabsf(q.w - mrb[3]);
#pragma unroll
        for (int m = 1; m < 8; m <<= 1) {
            pa_ += __shfl_xor(pa_, m, 64);
            pb_ += __shfl_xor(pb_, m, 64);
        }
        if (j == 0) { lds_fadd(&ia[la], pa_); lds_fadd(&ib[lb], pb_); }
    }
    __syncthreads();
    if (t < CDIM) {
        glob_fadd(&ws[2112 + t], ia[t]);
        glob_fadd(&ws[2144 + t], ib[t]);
    }
}

__global__ __launch_bounds__(64) void finalize_kernel(
    const float* __restrict__ ws, float* __restrict__ out, int nrows)
{
    __shared__ float tota[CDIM];
    __shared__ float totb[CDIM];
    int t = threadIdx.x;   // one wave: lanes 0..31 = tensor a, 32..63 = tensor b
    if (t < CDIM) {
        float sa_ = 0.f, sb_ = 0.f;
        for (int c = 0; c < CDIM; c++) {
            sa_ += ws[64 + c * 32 + t];
            sb_ += ws[64 + 1024 + c * 32 + t];
        }
        tota[t] = sa_; totb[t] = sb_;
    }
    __syncthreads();

    const int  c   = t & 31;
    const bool isA = (t < 32);
    const float* sums = isA ? (ws + 64) : (ws + 64 + 1024);
    const float* tot  = isA ? tota : totb;
    float cnt  = isA ? ws[c]        : ws[32 + c];
    float isum = isA ? ws[2112 + c] : ws[2144 + c];

    float safe = fmaxf(cnt, 1.0f);
    float invs = 1.0f / safe;
    float invo = 1.0f / fmaxf((float)nrows - cnt, 1.0f);
    float mad = 0.f;
    for (int d = 0; d < CDIM; d++) {
        float s = sums[c * 32 + d];
        float m = s * invs;                  // class mean
        float o = (tot[d] - s) * invo;       // complement mean
        mad += fabsf(m - o);
    }
    mad *= (1.0f / CDIM);
    float diff = expf(-5.0f * mad);
    float present = (cnt > 0.f) ? 1.f : 0.f;

    unsigned long long pm = __ballot(cnt > 0.f);
    int np = isA ? __popcll(pm & 0xFFFFFFFFull) : __popcll(pm >> 32);
    if (np <= 1) diff = 1.0f;                // only-one-class branch

    float intra   = isum * invs * (1.0f / CDIM);
    float contrib = present * (intra + diff);
    float pres    = present;
#pragma unroll
    for (int m = 1; m < 64; m <<= 1) {
        contrib += __shfl_xor(contrib, m, 64);
        pres    += __shfl_xor(pres,    m, 64);
    }
    if (t == 0) out[0] = contrib / (2.0f * pres);
}

extern "C" void kernel_launch(void* const* d_in, const int* in_sizes, int n_in,
                              void* d_out, int out_size, void* d_ws, size_t ws_size,
                              hipStream_t stream) {
    const float* pred   = (const float*)d_in[0];
    const float* pseudo = (const float*)d_in[1];
    float* ws  = (float*)d_ws;
    float* out = (float*)d_out;
    const int nrows = in_sizes[0] / CDIM;   // 2,000,000

    // ws is poisoned 0xAA before every timed launch — zero the accumulators.
    hipMemsetAsync(d_ws, 0, 2176 * sizeof(float), stream);

    dim3 grid(2048), block(256);  // 8 blocks/CU * 256 CUs => 32 waves/CU for latency hiding
    pass1_kernel<<<grid, block, 0, stream>>>(pred, pseudo, ws, nrows);
    pass2_kernel<<<grid, block, 0, stream>>>(pred, pseudo, ws, nrows);
    finalize_kernel<<<1, 64, 0, stream>>>(ws, out, nrows);
}

// Round 3
// 809.813 us; speedup vs baseline: 1.4166x; 1.4125x over previous
//
#include <hip/hip_runtime.h>

// LossClassInOut: pred, pseudo are [N=2e6, C=32] fp32. Output: scalar fp32.
//
// ws float layout (2176 floats):
//   [0,32) counts_a | [32,64) counts_b | [64,1088) sums_a[32][32]
//   [1088,2112) sums_b[32][32] | [2112,2144) intra_a | [2144,2176) intra_b
//
// R2 lesson: hot loop was DS-op bound (shfl_xor swizzles + per-element LDS
// atomics ~50-110cyc effective each; VALUBusy 3.7%, BW 5%). This version:
// no shuffles (per-lane register argmax after LDS transpose), no per-element
// atomics (one-hot bf16 MFMA computes the class sums), register-prefetch
// pipeline over wave-private tiles (no __syncthreads in the hot loop).

constexpr int CDIM = 32;
constexpr int NBLK = 512;            // 2 blocks/CU, exactly resident (73KB LDS each)
constexpr int ROWS_PER_BLOCK = 256;  // 4 waves * 64 rows

typedef __attribute__((ext_vector_type(8)))  short bf16x8;
typedef __attribute__((ext_vector_type(16))) float f32x16;

__device__ __forceinline__ unsigned short f2bf(float f) {
    unsigned u = __float_as_uint(f);
    return (unsigned short)((u + 0x7FFFu + ((u >> 16) & 1u)) >> 16);  // RNE
}
// float-index into a 64x32 tile stored as 128B rows with 16B-block XOR swizzle
__device__ __forceinline__ int toff(int r, int kb) {
    return r * 32 + ((kb ^ (r & 7)) * 4);
}
// np.argmax semantics: strict > keeps first index on ties
__device__ __forceinline__ int argmax_row(const float4* v) {
    float b = v[0].x; int bi = 0;
#pragma unroll
    for (int k = 0; k < 8; k++) {
        int k4 = k * 4;
        if (v[k].x > b) { b = v[k].x; bi = k4; }
        if (v[k].y > b) { b = v[k].y; bi = k4 + 1; }
        if (v[k].z > b) { b = v[k].z; bi = k4 + 2; }
        if (v[k].w > b) { b = v[k].w; bi = k4 + 3; }
    }
    return bi;
}

__global__ __launch_bounds__(256) void pass1_kernel(
    const float* __restrict__ pred, const float* __restrict__ pseudo,
    float* __restrict__ ws, int nrows)
{
    __shared__ __align__(16) float ptile[4][64 * 32];
    __shared__ __align__(16) float qtile[4][64 * 32];
    __shared__ __align__(16) unsigned short labs[4][64];
    __shared__ float sa[CDIM][33], sb[CDIM][33];
    __shared__ float ca[CDIM], cb[CDIM];

    const int t = threadIdx.x, wv = t >> 6, lw = t & 63;
    for (int i = t; i < CDIM * 33; i += 256) { (&sa[0][0])[i] = 0.f; (&sb[0][0])[i] = 0.f; }
    if (t < CDIM) { ca[t] = 0.f; cb[t] = 0.f; }
    __syncthreads();

    float* pt = ptile[wv];
    float* qt = qtile[wv];
    const int rl = lw >> 3, kb = lw & 7;   // staging coords
    const int n  = lw & 31, h  = lw >> 5;  // mfma lane coords

    f32x16 accP, accQ;
#pragma unroll
    for (int g = 0; g < 16; g++) { accP[g] = 0.f; accQ[g] = 0.f; }

    const float4* p4 = (const float4*)pred;
    const float4* q4 = (const float4*)pseudo;
    const long long rps = (long long)NBLK * ROWS_PER_BLOCK;
    const int nsweep = (int)((nrows + rps - 1) / rps);
    const long long wbase0 = (long long)blockIdx.x * ROWS_PER_BLOCK + wv * 64;

    float4 P[8], Q[8];
#pragma unroll
    for (int i = 0; i < 8; i++) {             // preload sweep 0
        long long r = wbase0 + rl + 8 * i; if (r >= nrows) r = nrows - 1;
        P[i] = p4[r * 8 + kb]; Q[i] = q4[r * 8 + kb];
    }

    for (int s = 0; s < nsweep; s++) {
        const long long wb = wbase0 + (long long)s * rps;
#pragma unroll
        for (int i = 0; i < 8; i++) {         // stage current tile
            *(float4*)&pt[toff(rl + 8 * i, kb)] = P[i];
            *(float4*)&qt[toff(rl + 8 * i, kb)] = Q[i];
        }
        if (s + 1 < nsweep) {                 // prefetch next sweep
            const long long wb2 = wb + rps;
#pragma unroll
            for (int i = 0; i < 8; i++) {
                long long r = wb2 + rl + 8 * i; if (r >= nrows) r = nrows - 1;
                P[i] = p4[r * 8 + kb]; Q[i] = q4[r * 8 + kb];
            }
        }
        // per-lane labels from register tournament (lane lw owns tile-row lw)
        const bool valid = (wb + lw) < nrows;
        int la, lbv;
        {
            float4 r_[8];
#pragma unroll
            for (int k = 0; k < 8; k++) r_[k] = *(const float4*)&qt[toff(lw, k)];
            la = argmax_row(r_);
#pragma unroll
            for (int k = 0; k < 8; k++) r_[k] = *(const float4*)&pt[toff(lw, k)];
            lbv = argmax_row(r_);
        }
        labs[wv][lw] = (unsigned short)((valid ? la : 0xFF) | ((valid ? lbv : 0xFF) << 8));
        unsafeAtomicAdd(&ca[la  & 31], valid ? 1.f : 0.f);
        unsafeAtomicAdd(&cb[lbv & 31], valid ? 1.f : 0.f);

        // one-hot MFMA: sums[c][d] += onehot(label)^T * X over 64 rows (K-tiles of 16)
#pragma unroll
        for (int kt = 0; kt < 4; kt++) {
            const uint4 lv = *(const uint4*)&labs[wv][kt * 16 + h * 8];  // 8 rows' packed labels
            bf16x8 aP, aQ, bP, bQ;
#pragma unroll
            for (int j = 0; j < 8; j++) {
                unsigned w32 = ((const unsigned*)&lv)[j >> 1];
                unsigned pr  = (w32 >> ((j & 1) * 16)) & 0xFFFFu;
                int laj = (int)(pr & 0xFF), lbj = (int)(pr >> 8);
                aP[j] = (short)((laj == n) ? 0x3F80 : 0);   // bf16 1.0 / 0.0
                aQ[j] = (short)((lbj == n) ? 0x3F80 : 0);
                int r = kt * 16 + h * 8 + j;
                int o = r * 32 + (((n >> 2) ^ (r & 7)) * 4) + (n & 3);
                bP[j] = (short)f2bf(pt[o]);
                bQ[j] = (short)f2bf(qt[o]);
            }
            accP = __builtin_amdgcn_mfma_f32_32x32x16_bf16(aP, bP, accP, 0, 0, 0);
            accQ = __builtin_amdgcn_mfma_f32_32x32x16_bf16(aQ, bQ, accQ, 0, 0, 0);
        }
    }

    // fold wave accumulators: C/D layout col=lane&31, row=(reg&3)+8*(reg>>2)+4*(lane>>5)
#pragma unroll
    for (int g = 0; g < 16; g++) {
        int c = (g & 3) + 8 * (g >> 2) + 4 * h;
        unsafeAtomicAdd(&sa[c][n], accP[g]);
        unsafeAtomicAdd(&sb[c][n], accQ[g]);
    }
    __syncthreads();
    for (int i = t; i < CDIM * CDIM; i += 256) {
        int c = i >> 5, d = i & 31;
        unsafeAtomicAdd(&ws[64 + i],        sa[c][d]);
        unsafeAtomicAdd(&ws[64 + 1024 + i], sb[c][d]);
    }
    if (t < CDIM) { unsafeAtomicAdd(&ws[t], ca[t]); unsafeAtomicAdd(&ws[32 + t], cb[t]); }
}

__global__ __launch_bounds__(256) void pass2_kernel(
    const float* __restrict__ pred, const float* __restrict__ pseudo,
    float* __restrict__ ws, int nrows)
{
    __shared__ __align__(16) float ptile[4][64 * 32];
    __shared__ __align__(16) float qtile[4][64 * 32];
    __shared__ __align__(16) float mA[1024], mB[1024];
    __shared__ float ia[CDIM], ib[CDIM];

    const int t = threadIdx.x, wv = t >> 6, lw = t & 63;
    for (int i = t; i < 1024; i += 256) {     // means, stored XOR-swizzled like tiles
        int c = i >> 5, d = i & 31;
        int o = c * 32 + (((d >> 2) ^ (c & 7)) * 4) + (d & 3);
        mA[o] = ws[64 + i]        / fmaxf(ws[c],      1.f);
        mB[o] = ws[64 + 1024 + i] / fmaxf(ws[32 + c], 1.f);
    }
    if (t < CDIM) { ia[t] = 0.f; ib[t] = 0.f; }
    __syncthreads();

    float* pt = ptile[wv];
    float* qt = qtile[wv];
    const int rl = lw >> 3, kb = lw & 7;

    const float4* p4 = (const float4*)pred;
    const float4* q4 = (const float4*)pseudo;
    const long long rps = (long long)NBLK * ROWS_PER_BLOCK;
    const int nsweep = (int)((nrows + rps - 1) / rps);
    const long long wbase0 = (long long)blockIdx.x * ROWS_PER_BLOCK + wv * 64;

    float4 P[8], Q[8];
#pragma unroll
    for (int i = 0; i < 8; i++) {
        long long r = wbase0 + rl + 8 * i; if (r >= nrows) r = nrows - 1;
        P[i] = p4[r * 8 + kb]; Q[i] = q4[r * 8 + kb];
    }

    for (int s = 0; s < nsweep; s++) {
        const long long wb = wbase0 + (long long)s * rps;
#pragma unroll
        for (int i = 0; i < 8; i++) {
            *(float4*)&pt[toff(rl + 8 * i, kb)] = P[i];
            *(float4*)&qt[toff(rl + 8 * i, kb)] = Q[i];
        }
        if (s + 1 < nsweep) {
            const long long wb2 = wb + rps;
#pragma unroll
            for (int i = 0; i < 8; i++) {
                long long r = wb2 + rl + 8 * i; if (r >= nrows) r = nrows - 1;
                P[i] = p4[r * 8 + kb]; Q[i] = q4[r * 8 + kb];
            }
        }
        const bool valid = (wb + lw) < nrows;
        float4 pr[8], qr[8];
#pragma unroll
        for (int k = 0; k < 8; k++) { pr[k] = *(const float4*)&pt[toff(lw, k)];
                                      qr[k] = *(const float4*)&qt[toff(lw, k)]; }
        const int la = argmax_row(qr) & 31;   // pseudo label -> segments pred
        const int lb = argmax_row(pr) & 31;   // pred label   -> segments pseudo
        float sA = 0.f, sB = 0.f;
#pragma unroll
        for (int k = 0; k < 8; k++) {
            float4 m4 = *(const float4*)&mA[la * 32 + ((k ^ (la & 7)) * 4)];
            sA += fabsf(pr[k].x - m4.x) + fabsf(pr[k].y - m4.y)
                + fabsf(pr[k].z - m4.z) + fabsf(pr[k].w - m4.w);
            float4 n4 = *(const float4*)&mB[lb * 32 + ((k ^ (lb & 7)) * 4)];
            sB += fabsf(qr[k].x - n4.x) + fabsf(qr[k].y - n4.y)
                + fabsf(qr[k].z - n4.z) + fabsf(qr[k].w - n4.w);
        }
        unsafeAtomicAdd(&ia[la], valid ? sA : 0.f);
        unsafeAtomicAdd(&ib[lb], valid ? sB : 0.f);
    }
    __syncthreads();
    if (t < CDIM) {
        unsafeAtomicAdd(&ws[2112 + t], ia[t]);
        unsafeAtomicAdd(&ws[2144 + t], ib[t]);
    }
}

__global__ __launch_bounds__(64) void finalize_kernel(
    const float* __restrict__ ws, float* __restrict__ out, int nrows)
{
    __shared__ float tota[CDIM];
    __shared__ float totb[CDIM];
    int t = threadIdx.x;   // lanes 0..31 = tensor a, 32..63 = tensor b
    if (t < CDIM) {
        float sa_ = 0.f, sb_ = 0.f;
        for (int c = 0; c < CDIM; c++) {
            sa_ += ws[64 + c * 32 + t];
            sb_ += ws[64 + 1024 + c * 32 + t];
        }
        tota[t] = sa_; totb[t] = sb_;
    }
    __syncthreads();

    const int  c   = t & 31;
    const bool isA = (t < 32);
    const float* sums = isA ? (ws + 64) : (ws + 64 + 1024);
    const float* tot  = isA ? tota : totb;
    float cnt  = isA ? ws[c]        : ws[32 + c];
    float isum = isA ? ws[2112 + c] : ws[2144 + c];

    float safe = fmaxf(cnt, 1.0f);
    float invs = 1.0f / safe;
    float invo = 1.0f / fmaxf((float)nrows - cnt, 1.0f);
    float mad = 0.f;
    for (int d = 0; d < CDIM; d++) {
        float s = sums[c * 32 + d];
        float m = s * invs;
        float o = (tot[d] - s) * invo;
        mad += fabsf(m - o);
    }
    mad *= (1.0f / CDIM);
    float diff = expf(-5.0f * mad);
    float present = (cnt > 0.f) ? 1.f : 0.f;

    unsigned long long pm = __ballot(cnt > 0.f);
    int np = isA ? __popcll(pm & 0xFFFFFFFFull) : __popcll(pm >> 32);
    if (np <= 1) diff = 1.0f;

    float intra   = isum * invs * (1.0f / CDIM);
    float contrib = present * (intra + diff);
    float pres    = present;
#pragma unroll
    for (int m = 1; m < 64; m <<= 1) {
        contrib += __shfl_xor(contrib, m, 64);
        pres    += __shfl_xor(pres,    m, 64);
    }
    if (t == 0) out[0] = contrib / (2.0f * pres);
}

extern "C" void kernel_launch(void* const* d_in, const int* in_sizes, int n_in,
                              void* d_out, int out_size, void* d_ws, size_t ws_size,
                              hipStream_t stream) {
    const float* pred   = (const float*)d_in[0];
    const float* pseudo = (const float*)d_in[1];
    float* ws  = (float*)d_ws;
    float* out = (float*)d_out;
    const int nrows = in_sizes[0] / CDIM;   // 2,000,000

    hipMemsetAsync(d_ws, 0, 2176 * sizeof(float), stream);

    dim3 grid(NBLK), block(256);
    pass1_kernel<<<grid, block, 0, stream>>>(pred, pseudo, ws, nrows);
    pass2_kernel<<<grid, block, 0, stream>>>(pred, pseudo, ws, nrows);
    finalize_kernel<<<1, 64, 0, stream>>>(ws, out, nrows);
}